// Round 12
// baseline (293.305 us; speedup 1.0000x reference)
//
#include <hip/hip_runtime.h>
#include <hip/hip_bf16.h>

#define TPB 256

typedef __attribute__((ext_vector_type(8))) short short8;
typedef __attribute__((ext_vector_type(4))) float f32x4;

__device__ __forceinline__ unsigned short f2bf(float f) {
    unsigned int u = __float_as_uint(f);
    u = (u + 0x7FFFu + ((u >> 16) & 1u)) >> 16;   // RNE
    return (unsigned short)u;
}
__device__ __forceinline__ float bflo(unsigned int u) { return __uint_as_float(u << 16); }
__device__ __forceinline__ float bfhi(unsigned int u) { return __uint_as_float(u & 0xFFFF0000u); }

// async global->LDS, 16B per lane; LDS dest is wave-uniform base + lane*16
__device__ __forceinline__ void gload16(const void* g, void* l) {
    __builtin_amdgcn_global_load_lds(
        (const __attribute__((address_space(1))) unsigned int*)g,
        (__attribute__((address_space(3))) unsigned int*)l, 16, 0, 0);
}

// ---------------- fused weight transpose + f32->bf16 for all 4 weights ----------------
__global__ void transpose_convert_all(
    const float* __restrict__ Wa, unsigned short* __restrict__ Ta, int Ka, int Na,
    const float* __restrict__ Wb, unsigned short* __restrict__ Tb, int Kb, int Nb,
    const float* __restrict__ Wc, unsigned short* __restrict__ Tc, int Kc, int Nc_,
    const float* __restrict__ Wd, unsigned short* __restrict__ Td, int Kd, int Nd)
{
    __shared__ float tile[32][33];
    int b = blockIdx.x;
    const float* W; unsigned short* T; int K, Nn;
    const int ta = (Na / 32) * (Ka / 32);
    const int tb = (Nb / 32) * (Kb / 32);
    const int tc = (Nc_ / 32) * (Kc / 32);
    if (b < ta)                { W = Wa; T = Ta; K = Ka; Nn = Na; }
    else if (b < ta + tb)      { b -= ta;           W = Wb; T = Tb; K = Kb; Nn = Nb; }
    else if (b < ta + tb + tc) { b -= ta + tb;      W = Wc; T = Tc; K = Kc; Nn = Nc_; }
    else                       { b -= ta + tb + tc; W = Wd; T = Td; K = Kd; Nn = Nd; }
    const int nx = Nn / 32;
    const int n0 = (b % nx) * 32;
    const int k0 = (b / nx) * 32;
    const int tx = threadIdx.x, ty = threadIdx.y;
#pragma unroll
    for (int i = 0; i < 4; ++i)
        tile[ty + i * 8][tx] = W[(size_t)(k0 + ty + i * 8) * Nn + n0 + tx];
    __syncthreads();
#pragma unroll
    for (int i = 0; i < 4; ++i)
        T[(size_t)(n0 + ty + i * 8) * K + k0 + tx] = f2bf(tile[tx][ty + i * 8]);
}

// ---------------- f32 A: 16 consecutive elements -> 2 bf16 short8 ----------------
__device__ __forceinline__ void load_a16f(const float* p, short8& lo, short8& hi) {
    float4 f0 = *reinterpret_cast<const float4*>(p);
    float4 f1 = *reinterpret_cast<const float4*>(p + 4);
    float4 f2 = *reinterpret_cast<const float4*>(p + 8);
    float4 f3 = *reinterpret_cast<const float4*>(p + 12);
    lo[0] = (short)f2bf(f0.x); lo[1] = (short)f2bf(f0.y);
    lo[2] = (short)f2bf(f0.z); lo[3] = (short)f2bf(f0.w);
    lo[4] = (short)f2bf(f1.x); lo[5] = (short)f2bf(f1.y);
    lo[6] = (short)f2bf(f1.z); lo[7] = (short)f2bf(f1.w);
    hi[0] = (short)f2bf(f2.x); hi[1] = (short)f2bf(f2.y);
    hi[2] = (short)f2bf(f2.z); hi[3] = (short)f2bf(f2.w);
    hi[4] = (short)f2bf(f3.x); hi[5] = (short)f2bf(f3.y);
    hi[6] = (short)f2bf(f3.z); hi[7] = (short)f2bf(f3.w);
}

// ---------------- epilogue copy-out of a 32x128 f32 LDS tile ----------------
__device__ __forceinline__ void copy_out32(unsigned short* C, const float* Cst, const float* bias,
                                           int rowbase, int bn, int M, int Nc, int t, bool doRelu) {
#pragma unroll
    for (int it = 0; it < 2; ++it) {
        const int idx = it * 2048 + t * 8;
        const int row = idx >> 7, col = idx & 127;
        const int m = rowbase + row;
        if (m >= M) continue;
        float4 v0 = *reinterpret_cast<const float4*>(&Cst[idx]);
        float4 v1 = *reinterpret_cast<const float4*>(&Cst[idx + 4]);
        float4 b0 = *reinterpret_cast<const float4*>(&bias[bn + col]);
        float4 b1 = *reinterpret_cast<const float4*>(&bias[bn + col + 4]);
        float o[8] = {v0.x + b0.x, v0.y + b0.y, v0.z + b0.z, v0.w + b0.w,
                      v1.x + b1.x, v1.y + b1.y, v1.z + b1.z, v1.w + b1.w};
        short8 s;
#pragma unroll
        for (int j = 0; j < 8; ++j) {
            const float vv = doRelu ? fmaxf(o[j], 0.f) : o[j];
            s[j] = (short)f2bf(vv);
        }
        *reinterpret_cast<short8*>(&C[(size_t)m * Nc + bn + col]) = s;
    }
}
__device__ __forceinline__ void copy_out32(float* C, const float* Cst, const float* bias,
                                           int rowbase, int bn, int M, int Nc, int t, bool doRelu) {
#pragma unroll
    for (int it = 0; it < 4; ++it) {
        const int idx = it * 1024 + t * 4;
        const int row = idx >> 7, col = idx & 127;
        const int m = rowbase + row;
        if (m >= M) continue;
        float4 v = *reinterpret_cast<const float4*>(&Cst[idx]);
        float4 b = *reinterpret_cast<const float4*>(&bias[bn + col]);
        v.x += b.x; v.y += b.y; v.z += b.z; v.w += b.w;
        if (doRelu) {
            v.x = fmaxf(v.x, 0.f); v.y = fmaxf(v.y, 0.f);
            v.z = fmaxf(v.z, 0.f); v.w = fmaxf(v.w, 0.f);
        }
        *reinterpret_cast<float4*>(&C[(size_t)m * Nc + bn + col]) = v;
    }
}

// ---------------- MFMA GEMM v4: 2-phase pipeline, double-buffered gload_lds ----------------
template <typename TA, typename TC, int K, bool RELU>
__global__ __launch_bounds__(256) void mfma_gemm4(
    const TA* __restrict__ A, const unsigned short* __restrict__ Bt,
    const float* __restrict__ bias, TC* __restrict__ C, int M, int Nc)
{
    __shared__ unsigned short lds_s[2][12288];     // 2 x 24 KB
    constexpr bool AF32 = (sizeof(TA) == 4);

    const int t  = threadIdx.x;
    const int l  = t & 63;
    const int w  = t >> 6;
    const int wm = w >> 1, wn = w & 1;             // wave tile 32x64
    const int bm = blockIdx.x * 64;
    const int bn = blockIdx.y * 128;

    f32x4 acc[2][4] = {};

    const int r4 = t >> 2;                         // row 0..63
    const int q4 = t & 3;                          // 16-elem group
    const int gmr = bm + r4;
    short8 sa0, sa1;

    auto loadAregs = [&](int k0) {
        if (gmr < M) load_a16f((const float*)A + (size_t)gmr * K + k0 + q4 * 16, sa0, sa1);
        else { sa0 = (short8)0; sa1 = (short8)0; }
    };
    auto writeAregs = [&](int buf) {
        const int s0 = (2 * q4)     ^ (r4 & 7);
        const int s1 = (2 * q4 + 1) ^ (r4 & 7);
        *reinterpret_cast<short8*>(&lds_s[buf][r4 * 64 + s0 * 8]) = sa0;
        *reinterpret_cast<short8*>(&lds_s[buf][r4 * 64 + s1 * 8]) = sa1;
    };
    auto stageA_lds = [&](int buf, int k0) {
#pragma unroll
        for (int ii = 0; ii < 2; ++ii) {
            const int seg = w + ii * 4;
            const int rr  = seg * 8 + (l >> 3);
            const int ss  = l & 7;
            const int gr  = min(bm + rr, M - 1);
            gload16((const unsigned short*)A + (size_t)gr * K + k0 + ((ss ^ (rr & 7)) * 8),
                    &lds_s[buf][seg * 512]);
        }
    };
    auto stageB = [&](int buf, int k0) {
#pragma unroll
        for (int ii = 0; ii < 4; ++ii) {
            const int seg = w + ii * 4;
            const int rr  = seg * 8 + (l >> 3);
            const int ss  = l & 7;
            gload16(Bt + (size_t)(bn + rr) * K + k0 + ((ss ^ (rr & 7)) * 8),
                    &lds_s[buf][4096 + seg * 512]);
        }
    };

    constexpr int S = K / 64;

    if (AF32) {
        loadAregs(0);
        writeAregs(0);
        if (S > 1) loadAregs(64);
    } else {
        stageA_lds(0, 0);
    }
    stageB(0, 0);
    __syncthreads();

#pragma unroll
    for (int step = 0; step < S; ++step) {
        const int k0  = step * 64;
        const int cur = step & 1;

        if (step + 1 < S) {
            if (AF32) writeAregs(cur ^ 1);
            else      stageA_lds(cur ^ 1, k0 + 64);
            stageB(cur ^ 1, k0 + 64);
        }
        if (AF32 && step + 2 < S) loadAregs(k0 + 128);

#pragma unroll
        for (int kk = 0; kk < 2; ++kk) {
            short8 af[2], bf4[4];
#pragma unroll
            for (int mf = 0; mf < 2; ++mf) {
                const int row  = wm * 32 + mf * 16 + (l & 15);
                const int slot = (kk * 4 + (l >> 4)) ^ (row & 7);
                af[mf] = *reinterpret_cast<const short8*>(&lds_s[cur][row * 64 + slot * 8]);
            }
#pragma unroll
            for (int nf = 0; nf < 4; ++nf) {
                const int row  = wn * 64 + nf * 16 + (l & 15);
                const int slot = (kk * 4 + (l >> 4)) ^ (row & 7);
                bf4[nf] = *reinterpret_cast<const short8*>(&lds_s[cur][4096 + row * 64 + slot * 8]);
            }
#pragma unroll
            for (int mf = 0; mf < 2; ++mf)
#pragma unroll
                for (int nf = 0; nf < 4; ++nf)
                    acc[mf][nf] = __builtin_amdgcn_mfma_f32_16x16x32_bf16(
                        af[mf], bf4[nf], acc[mf][nf], 0, 0, 0);
        }
        __syncthreads();
    }

    float* Cst = reinterpret_cast<float*>(lds_s);
#pragma unroll
    for (int p = 0; p < 2; ++p) {
        if (wm == p) {
#pragma unroll
            for (int mf = 0; mf < 2; ++mf)
#pragma unroll
                for (int nf = 0; nf < 4; ++nf)
#pragma unroll
                    for (int rr = 0; rr < 4; ++rr) {
                        const int row = mf * 16 + (l >> 4) * 4 + rr;
                        const int col = wn * 64 + nf * 16 + (l & 15);
                        Cst[row * 128 + col] = acc[mf][nf][rr];
                    }
        }
        __syncthreads();
        copy_out32(C, Cst, bias, bm + p * 32, bn, M, Nc, t, RELU);
        if (p == 0) __syncthreads();
    }
}

// ---------------- CSR build (XCD-chunked: chunk = blockIdx % 8 rides XCD round-robin) ----------------
// Each chunk's blocks scan ALL edges (dst is L3-resident) but touch only counts/cursor/perm
// in their own N/8 node slice -> per-XCD-private dirty lines, no cross-XCD write amplification.
__global__ void hist_kernel(const int* __restrict__ dst, int* __restrict__ counts,
                            int E, int csz)
{
    const int chunk = blockIdx.x & 7;
    const int blk   = blockIdx.x >> 3;
    const int lo = chunk * csz, hi = lo + csz;
    const int base = (blk * TPB + threadIdx.x) * 4;
    if (base + 3 < E) {
        int4 d4 = *reinterpret_cast<const int4*>(dst + base);
        if (d4.x >= lo && d4.x < hi) atomicAdd(&counts[d4.x], 1);
        if (d4.y >= lo && d4.y < hi) atomicAdd(&counts[d4.y], 1);
        if (d4.z >= lo && d4.z < hi) atomicAdd(&counts[d4.z], 1);
        if (d4.w >= lo && d4.w < hi) atomicAdd(&counts[d4.w], 1);
    } else {
        for (int e = base; e < E; ++e) {
            const int d = dst[e];
            if (d >= lo && d < hi) atomicAdd(&counts[d], 1);
        }
    }
}

__global__ void scan1_kernel(const int* __restrict__ counts,
                             int* __restrict__ local, int* __restrict__ bsum, int N)
{
    __shared__ int sh[TPB];
    const int t = threadIdx.x;
    const int base = blockIdx.x * 1024 + t * 4;
    int v[4];
#pragma unroll
    for (int i = 0; i < 4; ++i) v[i] = (base + i < N) ? counts[base + i] : 0;
    const int s = v[0] + v[1] + v[2] + v[3];
    sh[t] = s;
    __syncthreads();
    for (int d = 1; d < TPB; d <<= 1) {
        int x = (t >= d) ? sh[t - d] : 0;
        __syncthreads();
        sh[t] += x;
        __syncthreads();
    }
    int run = sh[t] - s;
#pragma unroll
    for (int i = 0; i < 4; ++i) {
        if (base + i < N) local[base + i] = run;
        run += v[i];
    }
    if (t == TPB - 1) bsum[blockIdx.x] = sh[TPB - 1];
}

__global__ void scan2_kernel(int* __restrict__ bsum, int nb)
{
    __shared__ int sh[TPB];
    const int t = threadIdx.x;
    const int v = (t < nb) ? bsum[t] : 0;
    sh[t] = v;
    __syncthreads();
    for (int d = 1; d < TPB; d <<= 1) {
        int x = (t >= d) ? sh[t - d] : 0;
        __syncthreads();
        sh[t] += x;
        __syncthreads();
    }
    if (t < nb) bsum[t] = sh[t] - v;
}

__global__ void scan3_kernel(int* __restrict__ offsets, int* __restrict__ cursor,
                             const int* __restrict__ bsum, int N)
{
    const int i = blockIdx.x * TPB + threadIdx.x;
    if (i < N) {
        const int o = offsets[i] + bsum[i >> 10];
        offsets[i] = o;
        cursor[i]  = o;
    }
}

__global__ void build_perm_kernel(const int* __restrict__ src, const int* __restrict__ dst,
                                  int* __restrict__ cursor, int* __restrict__ perm,
                                  int E, int csz)
{
    const int chunk = blockIdx.x & 7;
    const int blk   = blockIdx.x >> 3;
    const int lo = chunk * csz, hi = lo + csz;
    const int base = (blk * TPB + threadIdx.x) * 4;
    if (base + 3 < E) {
        int4 d4 = *reinterpret_cast<const int4*>(dst + base);
        if (d4.x >= lo && d4.x < hi) { int p = atomicAdd(&cursor[d4.x], 1); perm[p] = src[base + 0]; }
        if (d4.y >= lo && d4.y < hi) { int p = atomicAdd(&cursor[d4.y], 1); perm[p] = src[base + 1]; }
        if (d4.z >= lo && d4.z < hi) { int p = atomicAdd(&cursor[d4.z], 1); perm[p] = src[base + 2]; }
        if (d4.w >= lo && d4.w < hi) { int p = atomicAdd(&cursor[d4.w], 1); perm[p] = src[base + 3]; }
    } else {
        for (int e = base; e < E; ++e) {
            const int d = dst[e];
            if (d >= lo && d < hi) { int p = atomicAdd(&cursor[d], 1); perm[p] = src[e]; }
        }
    }
}

// ---------------- CSR gather aggregation (bf16, chunked, shfl-broadcast) ----------------
template <int F, int CH, bool WRITE_ZF32>
__global__ __launch_bounds__(256) void agg_kernel(
    const uint2* __restrict__ xt,
    const int* __restrict__ offsets, const int* __restrict__ counts,
    const int* __restrict__ perm,
    uint2* __restrict__ out, float* __restrict__ zf32, int N)
{
    constexpr int RU  = F / 4;
    constexpr int L   = RU / CH;
    constexpr int NPB = TPB / L;

    const int chunk = blockIdx.x % CH;
    const int node  = (blockIdx.x / CH) * NPB + threadIdx.x / L;
    const int g     = threadIdx.x % L;
    if (node >= N) return;
    const int col = chunk * L + g;

    const int start = offsets[node];
    const int deg   = counts[node];

    float a0 = 0.f, a1 = 0.f, a2 = 0.f, a3 = 0.f;

    for (int base = 0; base < deg; base += L) {
        const int m = min(L, deg - base);
        const int pidx = perm[start + base + ((g < m) ? g : (m - 1))];
        int j = 0;
        for (; j + 4 <= m; j += 4) {
            const int s0 = __shfl(pidx, j + 0, L);
            const int s1 = __shfl(pidx, j + 1, L);
            const int s2 = __shfl(pidx, j + 2, L);
            const int s3 = __shfl(pidx, j + 3, L);
            const uint2 v0 = xt[(size_t)s0 * RU + col];
            const uint2 v1 = xt[(size_t)s1 * RU + col];
            const uint2 v2 = xt[(size_t)s2 * RU + col];
            const uint2 v3 = xt[(size_t)s3 * RU + col];
            a0 += bflo(v0.x) + bflo(v1.x) + bflo(v2.x) + bflo(v3.x);
            a1 += bfhi(v0.x) + bfhi(v1.x) + bfhi(v2.x) + bfhi(v3.x);
            a2 += bflo(v0.y) + bflo(v1.y) + bflo(v2.y) + bflo(v3.y);
            a3 += bfhi(v0.y) + bfhi(v1.y) + bfhi(v2.y) + bfhi(v3.y);
        }
        for (; j < m; ++j) {
            const int s = __shfl(pidx, j, L);
            const uint2 v = xt[(size_t)s * RU + col];
            a0 += bflo(v.x); a1 += bfhi(v.x);
            a2 += bflo(v.y); a3 += bfhi(v.y);
        }
    }

    const float c = (float)max(deg, 1);
    const uint2 xv = xt[(size_t)node * RU + col];
    const float r0 = fmaxf(a0 / c, 0.f) + bflo(xv.x);
    const float r1 = fmaxf(a1 / c, 0.f) + bfhi(xv.x);
    const float r2 = fmaxf(a2 / c, 0.f) + bflo(xv.y);
    const float r3 = fmaxf(a3 / c, 0.f) + bfhi(xv.y);

    uint2 o;
    o.x = (unsigned int)f2bf(r0) | ((unsigned int)f2bf(r1) << 16);
    o.y = (unsigned int)f2bf(r2) | ((unsigned int)f2bf(r3) << 16);
    out[(size_t)node * RU + col] = o;
    if (WRITE_ZF32) {
        float4 z4 = make_float4(r0, r1, r2, r3);
        *reinterpret_cast<float4*>(&zf32[(size_t)node * F + 4 * col]) = z4;
    }
}

extern "C" void kernel_launch(void* const* d_in, const int* in_sizes, int n_in,
                              void* d_out, int out_size, void* d_ws, size_t ws_size,
                              hipStream_t stream)
{
    const int IN_DIM = 256, HID = 256, LAT = 128, DEC_HID = 512;
    const int N = in_sizes[0] / IN_DIM;     // 50000
    const int E = in_sizes[1] / 2;          // 800000

    const float* x   = (const float*)d_in[0];
    const int*   ei  = (const int*)d_in[1];
    const float* W1  = (const float*)d_in[2];
    const float* b1  = (const float*)d_in[3];
    const float* W2  = (const float*)d_in[4];
    const float* b2  = (const float*)d_in[5];
    const float* Wd1 = (const float*)d_in[6];
    const float* bd1 = (const float*)d_in[7];
    const float* Wd2 = (const float*)d_in[8];
    const float* bd2 = (const float*)d_in[9];

    const int* src = ei;
    const int* dst = ei + E;

    unsigned short* xt1  = (unsigned short*)d_ws;             // [N][256]
    unsigned short* h    = xt1  + (size_t)N * 256;            // [N][256]
    unsigned short* xt2  = h    + (size_t)N * 256;            // [N][128]
    unsigned short* zbf  = xt2  + (size_t)N * 128;            // [N][128]
    unsigned short* hdec = zbf  + (size_t)N * 128;            // [N][512]
    unsigned short* wt1  = hdec + (size_t)N * 512;            // [256][256]
    unsigned short* wt2  = wt1  + 256 * 256;                  // [128][256]
    unsigned short* wtd1 = wt2  + 128 * 256;                  // [512][128]
    unsigned short* wtd2 = wtd1 + 512 * 128;                  // [256][512]
    int* counts  = (int*)(wtd2 + 256 * 512);
    int* offsets = counts + N;
    int* cursor  = offsets + N;
    int* bsum    = cursor + N;
    int* perm    = bsum + 256;

    float* out_xhat = (float*)d_out;
    float* out_z    = out_xhat + (size_t)N * IN_DIM;

    dim3 blk(TPB);
    const int mb64 = (N + 63) / 64;
    const int nscan = (N + 1023) / 1024;
    const int csz = (N + 7) / 8;                               // node-slice per XCD chunk
    const int egrid8 = ((E + TPB * 4 - 1) / (TPB * 4)) * 8;    // chunked edge grid

    // ---- fused weight transpose/convert ----
    {
        const int tiles = (HID/32)*(IN_DIM/32) + (LAT/32)*(HID/32)
                        + (DEC_HID/32)*(LAT/32) + (IN_DIM/32)*(DEC_HID/32);
        transpose_convert_all<<<tiles, dim3(32, 8), 0, stream>>>(
            W1, wt1, IN_DIM, HID,  W2, wt2, HID, LAT,
            Wd1, wtd1, LAT, DEC_HID,  Wd2, wtd2, DEC_HID, IN_DIM);
    }

    // ---- CSR build (XCD-chunked hist + perm) ----
    hipMemsetAsync(counts, 0, (size_t)N * 4, stream);
    hist_kernel<<<egrid8, blk, 0, stream>>>(dst, counts, E, csz);
    scan1_kernel<<<nscan, blk, 0, stream>>>(counts, offsets, bsum, N);
    scan2_kernel<<<1, blk, 0, stream>>>(bsum, nscan);
    scan3_kernel<<<(N + TPB - 1) / TPB, blk, 0, stream>>>(offsets, cursor, bsum, N);
    build_perm_kernel<<<egrid8, blk, 0, stream>>>(src, dst, cursor, perm, E, csz);

    // ---- GCN layer 1 ----
    mfma_gemm4<float, unsigned short, 256, false><<<dim3(mb64, HID / 128), blk, 0, stream>>>(
        x, wt1, b1, xt1, N, HID);
    {   // F=256, CH=8 (8 lanes/node, 32 nodes/block) — per-XCD slice 3.2 MB, L2-fit probe
        const int ngroups = (N + 31) / 32;
        agg_kernel<256, 8, false><<<ngroups * 8, blk, 0, stream>>>(
            (const uint2*)xt1, offsets, counts, perm, (uint2*)h, nullptr, N);
    }

    // ---- GCN layer 2 ----
    mfma_gemm4<unsigned short, unsigned short, 256, false><<<dim3(mb64, LAT / 128), blk, 0, stream>>>(
        h, wt2, b2, xt2, N, LAT);
    {   // F=128, CH=1
        const int ngroups = (N + 7) / 8;
        agg_kernel<128, 1, true><<<ngroups, blk, 0, stream>>>(
            (const uint2*)xt2, offsets, counts, perm, (uint2*)zbf, out_z, N);
    }

    // ---- decoder ----
    mfma_gemm4<unsigned short, unsigned short, 128, true><<<dim3(mb64, DEC_HID / 128), blk, 0, stream>>>(
        zbf, wtd1, bd1, hdec, N, DEC_HID);
    mfma_gemm4<unsigned short, float, 512, false><<<dim3(mb64, IN_DIM / 128), blk, 0, stream>>>(
        hdec, wtd2, bd2, out_xhat, N, IN_DIM);
}

// Round 13
// 271.994 us; speedup vs baseline: 1.0784x; 1.0784x over previous
//
#include <hip/hip_runtime.h>
#include <hip/hip_bf16.h>

#define TPB 256

typedef __attribute__((ext_vector_type(8))) short short8;
typedef __attribute__((ext_vector_type(4))) float f32x4;

__device__ __forceinline__ unsigned short f2bf(float f) {
    unsigned int u = __float_as_uint(f);
    u = (u + 0x7FFFu + ((u >> 16) & 1u)) >> 16;   // RNE
    return (unsigned short)u;
}
__device__ __forceinline__ float bflo(unsigned int u) { return __uint_as_float(u << 16); }
__device__ __forceinline__ float bfhi(unsigned int u) { return __uint_as_float(u & 0xFFFF0000u); }

// async global->LDS, 16B per lane; LDS dest is wave-uniform base + lane*16
__device__ __forceinline__ void gload16(const void* g, void* l) {
    __builtin_amdgcn_global_load_lds(
        (const __attribute__((address_space(1))) unsigned int*)g,
        (__attribute__((address_space(3))) unsigned int*)l, 16, 0, 0);
}

// ---------------- fused weight transpose + f32->bf16 for all 4 weights ----------------
__global__ void transpose_convert_all(
    const float* __restrict__ Wa, unsigned short* __restrict__ Ta, int Ka, int Na,
    const float* __restrict__ Wb, unsigned short* __restrict__ Tb, int Kb, int Nb,
    const float* __restrict__ Wc, unsigned short* __restrict__ Tc, int Kc, int Nc_,
    const float* __restrict__ Wd, unsigned short* __restrict__ Td, int Kd, int Nd)
{
    __shared__ float tile[32][33];
    int b = blockIdx.x;
    const float* W; unsigned short* T; int K, Nn;
    const int ta = (Na / 32) * (Ka / 32);
    const int tb = (Nb / 32) * (Kb / 32);
    const int tc = (Nc_ / 32) * (Kc / 32);
    if (b < ta)                { W = Wa; T = Ta; K = Ka; Nn = Na; }
    else if (b < ta + tb)      { b -= ta;           W = Wb; T = Tb; K = Kb; Nn = Nb; }
    else if (b < ta + tb + tc) { b -= ta + tb;      W = Wc; T = Tc; K = Kc; Nn = Nc_; }
    else                       { b -= ta + tb + tc; W = Wd; T = Td; K = Kd; Nn = Nd; }
    const int nx = Nn / 32;
    const int n0 = (b % nx) * 32;
    const int k0 = (b / nx) * 32;
    const int tx = threadIdx.x, ty = threadIdx.y;
#pragma unroll
    for (int i = 0; i < 4; ++i)
        tile[ty + i * 8][tx] = W[(size_t)(k0 + ty + i * 8) * Nn + n0 + tx];
    __syncthreads();
#pragma unroll
    for (int i = 0; i < 4; ++i)
        T[(size_t)(n0 + ty + i * 8) * K + k0 + tx] = f2bf(tile[tx][ty + i * 8]);
}

// ---------------- f32 A: 16 consecutive elements -> 2 bf16 short8 ----------------
__device__ __forceinline__ void load_a16f(const float* p, short8& lo, short8& hi) {
    float4 f0 = *reinterpret_cast<const float4*>(p);
    float4 f1 = *reinterpret_cast<const float4*>(p + 4);
    float4 f2 = *reinterpret_cast<const float4*>(p + 8);
    float4 f3 = *reinterpret_cast<const float4*>(p + 12);
    lo[0] = (short)f2bf(f0.x); lo[1] = (short)f2bf(f0.y);
    lo[2] = (short)f2bf(f0.z); lo[3] = (short)f2bf(f0.w);
    lo[4] = (short)f2bf(f1.x); lo[5] = (short)f2bf(f1.y);
    lo[6] = (short)f2bf(f1.z); lo[7] = (short)f2bf(f1.w);
    hi[0] = (short)f2bf(f2.x); hi[1] = (short)f2bf(f2.y);
    hi[2] = (short)f2bf(f2.z); hi[3] = (short)f2bf(f2.w);
    hi[4] = (short)f2bf(f3.x); hi[5] = (short)f2bf(f3.y);
    hi[6] = (short)f2bf(f3.z); hi[7] = (short)f2bf(f3.w);
}

// ---------------- epilogue copy-out of a 32x128 f32 LDS tile ----------------
__device__ __forceinline__ void copy_out32(unsigned short* C, const float* Cst, const float* bias,
                                           int rowbase, int bn, int M, int Nc, int t, bool doRelu) {
#pragma unroll
    for (int it = 0; it < 2; ++it) {
        const int idx = it * 2048 + t * 8;
        const int row = idx >> 7, col = idx & 127;
        const int m = rowbase + row;
        if (m >= M) continue;
        float4 v0 = *reinterpret_cast<const float4*>(&Cst[idx]);
        float4 v1 = *reinterpret_cast<const float4*>(&Cst[idx + 4]);
        float4 b0 = *reinterpret_cast<const float4*>(&bias[bn + col]);
        float4 b1 = *reinterpret_cast<const float4*>(&bias[bn + col + 4]);
        float o[8] = {v0.x + b0.x, v0.y + b0.y, v0.z + b0.z, v0.w + b0.w,
                      v1.x + b1.x, v1.y + b1.y, v1.z + b1.z, v1.w + b1.w};
        short8 s;
#pragma unroll
        for (int j = 0; j < 8; ++j) {
            const float vv = doRelu ? fmaxf(o[j], 0.f) : o[j];
            s[j] = (short)f2bf(vv);
        }
        *reinterpret_cast<short8*>(&C[(size_t)m * Nc + bn + col]) = s;
    }
}
__device__ __forceinline__ void copy_out32(float* C, const float* Cst, const float* bias,
                                           int rowbase, int bn, int M, int Nc, int t, bool doRelu) {
#pragma unroll
    for (int it = 0; it < 4; ++it) {
        const int idx = it * 1024 + t * 4;
        const int row = idx >> 7, col = idx & 127;
        const int m = rowbase + row;
        if (m >= M) continue;
        float4 v = *reinterpret_cast<const float4*>(&Cst[idx]);
        float4 b = *reinterpret_cast<const float4*>(&bias[bn + col]);
        v.x += b.x; v.y += b.y; v.z += b.z; v.w += b.w;
        if (doRelu) {
            v.x = fmaxf(v.x, 0.f); v.y = fmaxf(v.y, 0.f);
            v.z = fmaxf(v.z, 0.f); v.w = fmaxf(v.w, 0.f);
        }
        *reinterpret_cast<float4*>(&C[(size_t)m * Nc + bn + col]) = v;
    }
}

// ---------------- MFMA GEMM v4: 2-phase pipeline, double-buffered gload_lds ----------------
template <typename TA, typename TC, int K, bool RELU>
__global__ __launch_bounds__(256) void mfma_gemm4(
    const TA* __restrict__ A, const unsigned short* __restrict__ Bt,
    const float* __restrict__ bias, TC* __restrict__ C, int M, int Nc)
{
    __shared__ unsigned short lds_s[2][12288];     // 2 x 24 KB
    constexpr bool AF32 = (sizeof(TA) == 4);

    const int t  = threadIdx.x;
    const int l  = t & 63;
    const int w  = t >> 6;
    const int wm = w >> 1, wn = w & 1;             // wave tile 32x64
    const int bm = blockIdx.x * 64;
    const int bn = blockIdx.y * 128;

    f32x4 acc[2][4] = {};

    const int r4 = t >> 2;                         // row 0..63
    const int q4 = t & 3;                          // 16-elem group
    const int gmr = bm + r4;
    short8 sa0, sa1;

    auto loadAregs = [&](int k0) {
        if (gmr < M) load_a16f((const float*)A + (size_t)gmr * K + k0 + q4 * 16, sa0, sa1);
        else { sa0 = (short8)0; sa1 = (short8)0; }
    };
    auto writeAregs = [&](int buf) {
        const int s0 = (2 * q4)     ^ (r4 & 7);
        const int s1 = (2 * q4 + 1) ^ (r4 & 7);
        *reinterpret_cast<short8*>(&lds_s[buf][r4 * 64 + s0 * 8]) = sa0;
        *reinterpret_cast<short8*>(&lds_s[buf][r4 * 64 + s1 * 8]) = sa1;
    };
    auto stageA_lds = [&](int buf, int k0) {
#pragma unroll
        for (int ii = 0; ii < 2; ++ii) {
            const int seg = w + ii * 4;
            const int rr  = seg * 8 + (l >> 3);
            const int ss  = l & 7;
            const int gr  = min(bm + rr, M - 1);
            gload16((const unsigned short*)A + (size_t)gr * K + k0 + ((ss ^ (rr & 7)) * 8),
                    &lds_s[buf][seg * 512]);
        }
    };
    auto stageB = [&](int buf, int k0) {
#pragma unroll
        for (int ii = 0; ii < 4; ++ii) {
            const int seg = w + ii * 4;
            const int rr  = seg * 8 + (l >> 3);
            const int ss  = l & 7;
            gload16(Bt + (size_t)(bn + rr) * K + k0 + ((ss ^ (rr & 7)) * 8),
                    &lds_s[buf][4096 + seg * 512]);
        }
    };

    constexpr int S = K / 64;

    if (AF32) {
        loadAregs(0);
        writeAregs(0);
        if (S > 1) loadAregs(64);
    } else {
        stageA_lds(0, 0);
    }
    stageB(0, 0);
    __syncthreads();

#pragma unroll
    for (int step = 0; step < S; ++step) {
        const int k0  = step * 64;
        const int cur = step & 1;

        if (step + 1 < S) {
            if (AF32) writeAregs(cur ^ 1);
            else      stageA_lds(cur ^ 1, k0 + 64);
            stageB(cur ^ 1, k0 + 64);
        }
        if (AF32 && step + 2 < S) loadAregs(k0 + 128);

#pragma unroll
        for (int kk = 0; kk < 2; ++kk) {
            short8 af[2], bf4[4];
#pragma unroll
            for (int mf = 0; mf < 2; ++mf) {
                const int row  = wm * 32 + mf * 16 + (l & 15);
                const int slot = (kk * 4 + (l >> 4)) ^ (row & 7);
                af[mf] = *reinterpret_cast<const short8*>(&lds_s[cur][row * 64 + slot * 8]);
            }
#pragma unroll
            for (int nf = 0; nf < 4; ++nf) {
                const int row  = wn * 64 + nf * 16 + (l & 15);
                const int slot = (kk * 4 + (l >> 4)) ^ (row & 7);
                bf4[nf] = *reinterpret_cast<const short8*>(&lds_s[cur][4096 + row * 64 + slot * 8]);
            }
#pragma unroll
            for (int mf = 0; mf < 2; ++mf)
#pragma unroll
                for (int nf = 0; nf < 4; ++nf)
                    acc[mf][nf] = __builtin_amdgcn_mfma_f32_16x16x32_bf16(
                        af[mf], bf4[nf], acc[mf][nf], 0, 0, 0);
        }
        __syncthreads();
    }

    float* Cst = reinterpret_cast<float*>(lds_s);
#pragma unroll
    for (int p = 0; p < 2; ++p) {
        if (wm == p) {
#pragma unroll
            for (int mf = 0; mf < 2; ++mf)
#pragma unroll
                for (int nf = 0; nf < 4; ++nf)
#pragma unroll
                    for (int rr = 0; rr < 4; ++rr) {
                        const int row = mf * 16 + (l >> 4) * 4 + rr;
                        const int col = wn * 64 + nf * 16 + (l & 15);
                        Cst[row * 128 + col] = acc[mf][nf][rr];
                    }
        }
        __syncthreads();
        copy_out32(C, Cst, bias, bm + p * 32, bn, M, Nc, t, RELU);
        if (p == 0) __syncthreads();
    }
}

// ---------------- CSR build (XCD-chunked) ----------------
__global__ void hist_kernel(const int* __restrict__ dst, int* __restrict__ counts,
                            int E, int csz)
{
    const int chunk = blockIdx.x & 7;
    const int blk   = blockIdx.x >> 3;
    const int lo = chunk * csz, hi = lo + csz;
    const int base = (blk * TPB + threadIdx.x) * 4;
    if (base + 3 < E) {
        int4 d4 = *reinterpret_cast<const int4*>(dst + base);
        if (d4.x >= lo && d4.x < hi) atomicAdd(&counts[d4.x], 1);
        if (d4.y >= lo && d4.y < hi) atomicAdd(&counts[d4.y], 1);
        if (d4.z >= lo && d4.z < hi) atomicAdd(&counts[d4.z], 1);
        if (d4.w >= lo && d4.w < hi) atomicAdd(&counts[d4.w], 1);
    } else {
        for (int e = base; e < E; ++e) {
            const int d = dst[e];
            if (d >= lo && d < hi) atomicAdd(&counts[d], 1);
        }
    }
}

__global__ void scan1_kernel(const int* __restrict__ counts,
                             int* __restrict__ local, int* __restrict__ bsum, int N)
{
    __shared__ int sh[TPB];
    const int t = threadIdx.x;
    const int base = blockIdx.x * 1024 + t * 4;
    int v[4];
#pragma unroll
    for (int i = 0; i < 4; ++i) v[i] = (base + i < N) ? counts[base + i] : 0;
    const int s = v[0] + v[1] + v[2] + v[3];
    sh[t] = s;
    __syncthreads();
    for (int d = 1; d < TPB; d <<= 1) {
        int x = (t >= d) ? sh[t - d] : 0;
        __syncthreads();
        sh[t] += x;
        __syncthreads();
    }
    int run = sh[t] - s;
#pragma unroll
    for (int i = 0; i < 4; ++i) {
        if (base + i < N) local[base + i] = run;
        run += v[i];
    }
    if (t == TPB - 1) bsum[blockIdx.x] = sh[TPB - 1];
}

__global__ void scan2_kernel(int* __restrict__ bsum, int nb)
{
    __shared__ int sh[TPB];
    const int t = threadIdx.x;
    const int v = (t < nb) ? bsum[t] : 0;
    sh[t] = v;
    __syncthreads();
    for (int d = 1; d < TPB; d <<= 1) {
        int x = (t >= d) ? sh[t - d] : 0;
        __syncthreads();
        sh[t] += x;
        __syncthreads();
    }
    if (t < nb) bsum[t] = sh[t] - v;
}

__global__ void scan3_kernel(int* __restrict__ offsets, int* __restrict__ cursor,
                             const int* __restrict__ bsum, int N)
{
    const int i = blockIdx.x * TPB + threadIdx.x;
    if (i < N) {
        const int o = offsets[i] + bsum[i >> 10];
        offsets[i] = o;
        cursor[i]  = o;
    }
}

__global__ void build_perm_kernel(const int* __restrict__ src, const int* __restrict__ dst,
                                  int* __restrict__ cursor, int* __restrict__ perm,
                                  int E, int csz)
{
    const int chunk = blockIdx.x & 7;
    const int blk   = blockIdx.x >> 3;
    const int lo = chunk * csz, hi = lo + csz;
    const int base = (blk * TPB + threadIdx.x) * 4;
    if (base + 3 < E) {
        int4 d4 = *reinterpret_cast<const int4*>(dst + base);
        if (d4.x >= lo && d4.x < hi) { int p = atomicAdd(&cursor[d4.x], 1); perm[p] = src[base + 0]; }
        if (d4.y >= lo && d4.y < hi) { int p = atomicAdd(&cursor[d4.y], 1); perm[p] = src[base + 1]; }
        if (d4.z >= lo && d4.z < hi) { int p = atomicAdd(&cursor[d4.z], 1); perm[p] = src[base + 2]; }
        if (d4.w >= lo && d4.w < hi) { int p = atomicAdd(&cursor[d4.w], 1); perm[p] = src[base + 3]; }
    } else {
        for (int e = base; e < E; ++e) {
            const int d = dst[e];
            if (d >= lo && d < hi) { int p = atomicAdd(&cursor[d], 1); perm[p] = src[e]; }
        }
    }
}

// ---------------- CSR gather aggregation (bf16, chunked, shfl-broadcast) ----------------
template <int F, int CH, bool WRITE_ZF32>
__global__ __launch_bounds__(256) void agg_kernel(
    const uint2* __restrict__ xt,
    const int* __restrict__ offsets, const int* __restrict__ counts,
    const int* __restrict__ perm,
    uint2* __restrict__ out, float* __restrict__ zf32, int N)
{
    constexpr int RU  = F / 4;
    constexpr int L   = RU / CH;
    constexpr int NPB = TPB / L;

    const int chunk = blockIdx.x % CH;
    const int node  = (blockIdx.x / CH) * NPB + threadIdx.x / L;
    const int g     = threadIdx.x % L;
    if (node >= N) return;
    const int col = chunk * L + g;

    const int start = offsets[node];
    const int deg   = counts[node];

    float a0 = 0.f, a1 = 0.f, a2 = 0.f, a3 = 0.f;

    for (int base = 0; base < deg; base += L) {
        const int m = min(L, deg - base);
        const int pidx = perm[start + base + ((g < m) ? g : (m - 1))];
        int j = 0;
        for (; j + 4 <= m; j += 4) {
            const int s0 = __shfl(pidx, j + 0, L);
            const int s1 = __shfl(pidx, j + 1, L);
            const int s2 = __shfl(pidx, j + 2, L);
            const int s3 = __shfl(pidx, j + 3, L);
            const uint2 v0 = xt[(size_t)s0 * RU + col];
            const uint2 v1 = xt[(size_t)s1 * RU + col];
            const uint2 v2 = xt[(size_t)s2 * RU + col];
            const uint2 v3 = xt[(size_t)s3 * RU + col];
            a0 += bflo(v0.x) + bflo(v1.x) + bflo(v2.x) + bflo(v3.x);
            a1 += bfhi(v0.x) + bfhi(v1.x) + bfhi(v2.x) + bfhi(v3.x);
            a2 += bflo(v0.y) + bflo(v1.y) + bflo(v2.y) + bflo(v3.y);
            a3 += bfhi(v0.y) + bfhi(v1.y) + bfhi(v2.y) + bfhi(v3.y);
        }
        for (; j < m; ++j) {
            const int s = __shfl(pidx, j, L);
            const uint2 v = xt[(size_t)s * RU + col];
            a0 += bflo(v.x); a1 += bfhi(v.x);
            a2 += bflo(v.y); a3 += bfhi(v.y);
        }
    }

    const float c = (float)max(deg, 1);
    const uint2 xv = xt[(size_t)node * RU + col];
    const float r0 = fmaxf(a0 / c, 0.f) + bflo(xv.x);
    const float r1 = fmaxf(a1 / c, 0.f) + bfhi(xv.x);
    const float r2 = fmaxf(a2 / c, 0.f) + bflo(xv.y);
    const float r3 = fmaxf(a3 / c, 0.f) + bfhi(xv.y);

    uint2 o;
    o.x = (unsigned int)f2bf(r0) | ((unsigned int)f2bf(r1) << 16);
    o.y = (unsigned int)f2bf(r2) | ((unsigned int)f2bf(r3) << 16);
    out[(size_t)node * RU + col] = o;
    if (WRITE_ZF32) {
        float4 z4 = make_float4(r0, r1, r2, r3);
        *reinterpret_cast<float4*>(&zf32[(size_t)node * F + 4 * col]) = z4;
    }
}

extern "C" void kernel_launch(void* const* d_in, const int* in_sizes, int n_in,
                              void* d_out, int out_size, void* d_ws, size_t ws_size,
                              hipStream_t stream)
{
    const int IN_DIM = 256, HID = 256, LAT = 128, DEC_HID = 512;
    const int N = in_sizes[0] / IN_DIM;     // 50000
    const int E = in_sizes[1] / 2;          // 800000

    const float* x   = (const float*)d_in[0];
    const int*   ei  = (const int*)d_in[1];
    const float* W1  = (const float*)d_in[2];
    const float* b1  = (const float*)d_in[3];
    const float* W2  = (const float*)d_in[4];
    const float* b2  = (const float*)d_in[5];
    const float* Wd1 = (const float*)d_in[6];
    const float* bd1 = (const float*)d_in[7];
    const float* Wd2 = (const float*)d_in[8];
    const float* bd2 = (const float*)d_in[9];

    const int* src = ei;
    const int* dst = ei + E;

    unsigned short* xt1  = (unsigned short*)d_ws;             // [N][256]
    unsigned short* h    = xt1  + (size_t)N * 256;            // [N][256]
    unsigned short* xt2  = h    + (size_t)N * 256;            // [N][128]
    unsigned short* zbf  = xt2  + (size_t)N * 128;            // [N][128]
    unsigned short* hdec = zbf  + (size_t)N * 128;            // [N][512]
    unsigned short* wt1  = hdec + (size_t)N * 512;            // [256][256]
    unsigned short* wt2  = wt1  + 256 * 256;                  // [128][256]
    unsigned short* wtd1 = wt2  + 128 * 256;                  // [512][128]
    unsigned short* wtd2 = wtd1 + 512 * 128;                  // [256][512]
    int* counts  = (int*)(wtd2 + 256 * 512);
    int* offsets = counts + N;
    int* cursor  = offsets + N;
    int* bsum    = cursor + N;
    int* perm    = bsum + 256;

    float* out_xhat = (float*)d_out;
    float* out_z    = out_xhat + (size_t)N * IN_DIM;

    dim3 blk(TPB);
    const int mb64 = (N + 63) / 64;
    const int nscan = (N + 1023) / 1024;
    const int csz = (N + 7) / 8;                               // node-slice per XCD chunk
    const int egrid8 = ((E + TPB * 4 - 1) / (TPB * 4)) * 8;    // chunked edge grid

    // ---- fused weight transpose/convert ----
    {
        const int tiles = (HID/32)*(IN_DIM/32) + (LAT/32)*(HID/32)
                        + (DEC_HID/32)*(LAT/32) + (IN_DIM/32)*(DEC_HID/32);
        transpose_convert_all<<<tiles, dim3(32, 8), 0, stream>>>(
            W1, wt1, IN_DIM, HID,  W2, wt2, HID, LAT,
            Wd1, wtd1, LAT, DEC_HID,  Wd2, wtd2, DEC_HID, IN_DIM);
    }

    // ---- CSR build (XCD-chunked hist + perm) ----
    hipMemsetAsync(counts, 0, (size_t)N * 4, stream);
    hist_kernel<<<egrid8, blk, 0, stream>>>(dst, counts, E, csz);
    scan1_kernel<<<nscan, blk, 0, stream>>>(counts, offsets, bsum, N);
    scan2_kernel<<<1, blk, 0, stream>>>(bsum, nscan);
    scan3_kernel<<<(N + TPB - 1) / TPB, blk, 0, stream>>>(offsets, cursor, bsum, N);
    build_perm_kernel<<<egrid8, blk, 0, stream>>>(src, dst, cursor, perm, E, csz);

    // ---- GCN layer 1 ----
    mfma_gemm4<float, unsigned short, 256, false><<<dim3(mb64, HID / 128), blk, 0, stream>>>(
        x, wt1, b1, xt1, N, HID);
    {   // F=256, CH=4 (16 lanes/node, 16 nodes/block): 128 B/chunk-row = 1 line
        const int ngroups = (N + 15) / 16;
        agg_kernel<256, 4, false><<<ngroups * 4, blk, 0, stream>>>(
            (const uint2*)xt1, offsets, counts, perm, (uint2*)h, nullptr, N);
    }

    // ---- GCN layer 2 ----
    mfma_gemm4<unsigned short, unsigned short, 256, false><<<dim3(mb64, LAT / 128), blk, 0, stream>>>(
        h, wt2, b2, xt2, N, LAT);
    {   // F=128, CH=2 (16 lanes/node, 16 nodes/block): 128 B/chunk-row = 1 line
        const int ngroups = (N + 15) / 16;
        agg_kernel<128, 2, true><<<ngroups * 2, blk, 0, stream>>>(
            (const uint2*)xt2, offsets, counts, perm, (uint2*)zbf, out_z, N);
    }

    // ---- decoder ----
    mfma_gemm4<unsigned short, unsigned short, 128, true><<<dim3(mb64, DEC_HID / 128), blk, 0, stream>>>(
        zbf, wtd1, bd1, hdec, N, DEC_HID);
    mfma_gemm4<unsigned short, float, 512, false><<<dim3(mb64, IN_DIM / 128), blk, 0, stream>>>(
        hdec, wtd2, bd2, out_xhat, N, IN_DIM);
}

// Round 14
// 266.977 us; speedup vs baseline: 1.0986x; 1.0188x over previous
//
#include <hip/hip_runtime.h>
#include <hip/hip_bf16.h>

#define TPB 256

typedef __attribute__((ext_vector_type(8))) short short8;
typedef __attribute__((ext_vector_type(4))) float f32x4;

__device__ __forceinline__ unsigned short f2bf(float f) {
    unsigned int u = __float_as_uint(f);
    u = (u + 0x7FFFu + ((u >> 16) & 1u)) >> 16;   // RNE
    return (unsigned short)u;
}
__device__ __forceinline__ float bflo(unsigned int u) { return __uint_as_float(u << 16); }
__device__ __forceinline__ float bfhi(unsigned int u) { return __uint_as_float(u & 0xFFFF0000u); }

// async global->LDS, 16B per lane; LDS dest is wave-uniform base + lane*16
__device__ __forceinline__ void gload16(const void* g, void* l) {
    __builtin_amdgcn_global_load_lds(
        (const __attribute__((address_space(1))) unsigned int*)g,
        (__attribute__((address_space(3))) unsigned int*)l, 16, 0, 0);
}

// ---------------- fused weight transpose + f32->bf16 for all 4 weights ----------------
__global__ void transpose_convert_all(
    const float* __restrict__ Wa, unsigned short* __restrict__ Ta, int Ka, int Na,
    const float* __restrict__ Wb, unsigned short* __restrict__ Tb, int Kb, int Nb,
    const float* __restrict__ Wc, unsigned short* __restrict__ Tc, int Kc, int Nc_,
    const float* __restrict__ Wd, unsigned short* __restrict__ Td, int Kd, int Nd)
{
    __shared__ float tile[32][33];
    int b = blockIdx.x;
    const float* W; unsigned short* T; int K, Nn;
    const int ta = (Na / 32) * (Ka / 32);
    const int tb = (Nb / 32) * (Kb / 32);
    const int tc = (Nc_ / 32) * (Kc / 32);
    if (b < ta)                { W = Wa; T = Ta; K = Ka; Nn = Na; }
    else if (b < ta + tb)      { b -= ta;           W = Wb; T = Tb; K = Kb; Nn = Nb; }
    else if (b < ta + tb + tc) { b -= ta + tb;      W = Wc; T = Tc; K = Kc; Nn = Nc_; }
    else                       { b -= ta + tb + tc; W = Wd; T = Td; K = Kd; Nn = Nd; }
    const int nx = Nn / 32;
    const int n0 = (b % nx) * 32;
    const int k0 = (b / nx) * 32;
    const int tx = threadIdx.x, ty = threadIdx.y;
#pragma unroll
    for (int i = 0; i < 4; ++i)
        tile[ty + i * 8][tx] = W[(size_t)(k0 + ty + i * 8) * Nn + n0 + tx];
    __syncthreads();
#pragma unroll
    for (int i = 0; i < 4; ++i)
        T[(size_t)(n0 + ty + i * 8) * K + k0 + tx] = f2bf(tile[tx][ty + i * 8]);
}

// ---------------- f32 A: 16 consecutive elements -> 2 bf16 short8 ----------------
__device__ __forceinline__ void load_a16f(const float* p, short8& lo, short8& hi) {
    float4 f0 = *reinterpret_cast<const float4*>(p);
    float4 f1 = *reinterpret_cast<const float4*>(p + 4);
    float4 f2 = *reinterpret_cast<const float4*>(p + 8);
    float4 f3 = *reinterpret_cast<const float4*>(p + 12);
    lo[0] = (short)f2bf(f0.x); lo[1] = (short)f2bf(f0.y);
    lo[2] = (short)f2bf(f0.z); lo[3] = (short)f2bf(f0.w);
    lo[4] = (short)f2bf(f1.x); lo[5] = (short)f2bf(f1.y);
    lo[6] = (short)f2bf(f1.z); lo[7] = (short)f2bf(f1.w);
    hi[0] = (short)f2bf(f2.x); hi[1] = (short)f2bf(f2.y);
    hi[2] = (short)f2bf(f2.z); hi[3] = (short)f2bf(f2.w);
    hi[4] = (short)f2bf(f3.x); hi[5] = (short)f2bf(f3.y);
    hi[6] = (short)f2bf(f3.z); hi[7] = (short)f2bf(f3.w);
}

// ---------------- epilogue copy-out of a 32x128 f32 LDS tile ----------------
__device__ __forceinline__ void copy_out32(unsigned short* C, const float* Cst, const float* bias,
                                           int rowbase, int bn, int M, int Nc, int t, bool doRelu) {
#pragma unroll
    for (int it = 0; it < 2; ++it) {
        const int idx = it * 2048 + t * 8;
        const int row = idx >> 7, col = idx & 127;
        const int m = rowbase + row;
        if (m >= M) continue;
        float4 v0 = *reinterpret_cast<const float4*>(&Cst[idx]);
        float4 v1 = *reinterpret_cast<const float4*>(&Cst[idx + 4]);
        float4 b0 = *reinterpret_cast<const float4*>(&bias[bn + col]);
        float4 b1 = *reinterpret_cast<const float4*>(&bias[bn + col + 4]);
        float o[8] = {v0.x + b0.x, v0.y + b0.y, v0.z + b0.z, v0.w + b0.w,
                      v1.x + b1.x, v1.y + b1.y, v1.z + b1.z, v1.w + b1.w};
        short8 s;
#pragma unroll
        for (int j = 0; j < 8; ++j) {
            const float vv = doRelu ? fmaxf(o[j], 0.f) : o[j];
            s[j] = (short)f2bf(vv);
        }
        *reinterpret_cast<short8*>(&C[(size_t)m * Nc + bn + col]) = s;
    }
}
__device__ __forceinline__ void copy_out32(float* C, const float* Cst, const float* bias,
                                           int rowbase, int bn, int M, int Nc, int t, bool doRelu) {
#pragma unroll
    for (int it = 0; it < 4; ++it) {
        const int idx = it * 1024 + t * 4;
        const int row = idx >> 7, col = idx & 127;
        const int m = rowbase + row;
        if (m >= M) continue;
        float4 v = *reinterpret_cast<const float4*>(&Cst[idx]);
        float4 b = *reinterpret_cast<const float4*>(&bias[bn + col]);
        v.x += b.x; v.y += b.y; v.z += b.z; v.w += b.w;
        if (doRelu) {
            v.x = fmaxf(v.x, 0.f); v.y = fmaxf(v.y, 0.f);
            v.z = fmaxf(v.z, 0.f); v.w = fmaxf(v.w, 0.f);
        }
        *reinterpret_cast<float4*>(&C[(size_t)m * Nc + bn + col]) = v;
    }
}

// ---------------- MFMA GEMM v4: 2-phase pipeline, double-buffered gload_lds ----------------
template <typename TA, typename TC, int K, bool RELU>
__global__ __launch_bounds__(256) void mfma_gemm4(
    const TA* __restrict__ A, const unsigned short* __restrict__ Bt,
    const float* __restrict__ bias, TC* __restrict__ C, int M, int Nc)
{
    __shared__ unsigned short lds_s[2][12288];     // 2 x 24 KB
    constexpr bool AF32 = (sizeof(TA) == 4);

    const int t  = threadIdx.x;
    const int l  = t & 63;
    const int w  = t >> 6;
    const int wm = w >> 1, wn = w & 1;             // wave tile 32x64
    const int bm = blockIdx.x * 64;
    const int bn = blockIdx.y * 128;

    f32x4 acc[2][4] = {};

    const int r4 = t >> 2;                         // row 0..63
    const int q4 = t & 3;                          // 16-elem group
    const int gmr = bm + r4;
    short8 sa0, sa1;

    auto loadAregs = [&](int k0) {
        if (gmr < M) load_a16f((const float*)A + (size_t)gmr * K + k0 + q4 * 16, sa0, sa1);
        else { sa0 = (short8)0; sa1 = (short8)0; }
    };
    auto writeAregs = [&](int buf) {
        const int s0 = (2 * q4)     ^ (r4 & 7);
        const int s1 = (2 * q4 + 1) ^ (r4 & 7);
        *reinterpret_cast<short8*>(&lds_s[buf][r4 * 64 + s0 * 8]) = sa0;
        *reinterpret_cast<short8*>(&lds_s[buf][r4 * 64 + s1 * 8]) = sa1;
    };
    auto stageA_lds = [&](int buf, int k0) {
#pragma unroll
        for (int ii = 0; ii < 2; ++ii) {
            const int seg = w + ii * 4;
            const int rr  = seg * 8 + (l >> 3);
            const int ss  = l & 7;
            const int gr  = min(bm + rr, M - 1);
            gload16((const unsigned short*)A + (size_t)gr * K + k0 + ((ss ^ (rr & 7)) * 8),
                    &lds_s[buf][seg * 512]);
        }
    };
    auto stageB = [&](int buf, int k0) {
#pragma unroll
        for (int ii = 0; ii < 4; ++ii) {
            const int seg = w + ii * 4;
            const int rr  = seg * 8 + (l >> 3);
            const int ss  = l & 7;
            gload16(Bt + (size_t)(bn + rr) * K + k0 + ((ss ^ (rr & 7)) * 8),
                    &lds_s[buf][4096 + seg * 512]);
        }
    };

    constexpr int S = K / 64;

    if (AF32) {
        loadAregs(0);
        writeAregs(0);
        if (S > 1) loadAregs(64);
    } else {
        stageA_lds(0, 0);
    }
    stageB(0, 0);
    __syncthreads();

#pragma unroll
    for (int step = 0; step < S; ++step) {
        const int k0  = step * 64;
        const int cur = step & 1;

        if (step + 1 < S) {
            if (AF32) writeAregs(cur ^ 1);
            else      stageA_lds(cur ^ 1, k0 + 64);
            stageB(cur ^ 1, k0 + 64);
        }
        if (AF32 && step + 2 < S) loadAregs(k0 + 128);

#pragma unroll
        for (int kk = 0; kk < 2; ++kk) {
            short8 af[2], bf4[4];
#pragma unroll
            for (int mf = 0; mf < 2; ++mf) {
                const int row  = wm * 32 + mf * 16 + (l & 15);
                const int slot = (kk * 4 + (l >> 4)) ^ (row & 7);
                af[mf] = *reinterpret_cast<const short8*>(&lds_s[cur][row * 64 + slot * 8]);
            }
#pragma unroll
            for (int nf = 0; nf < 4; ++nf) {
                const int row  = wn * 64 + nf * 16 + (l & 15);
                const int slot = (kk * 4 + (l >> 4)) ^ (row & 7);
                bf4[nf] = *reinterpret_cast<const short8*>(&lds_s[cur][4096 + row * 64 + slot * 8]);
            }
#pragma unroll
            for (int mf = 0; mf < 2; ++mf)
#pragma unroll
                for (int nf = 0; nf < 4; ++nf)
                    acc[mf][nf] = __builtin_amdgcn_mfma_f32_16x16x32_bf16(
                        af[mf], bf4[nf], acc[mf][nf], 0, 0, 0);
        }
        __syncthreads();
    }

    float* Cst = reinterpret_cast<float*>(lds_s);
#pragma unroll
    for (int p = 0; p < 2; ++p) {
        if (wm == p) {
#pragma unroll
            for (int mf = 0; mf < 2; ++mf)
#pragma unroll
                for (int nf = 0; nf < 4; ++nf)
#pragma unroll
                    for (int rr = 0; rr < 4; ++rr) {
                        const int row = mf * 16 + (l >> 4) * 4 + rr;
                        const int col = wn * 64 + nf * 16 + (l & 15);
                        Cst[row * 128 + col] = acc[mf][nf][rr];
                    }
        }
        __syncthreads();
        copy_out32(C, Cst, bias, bm + p * 32, bn, M, Nc, t, RELU);
        if (p == 0) __syncthreads();
    }
}

// ---------------- fused decoder: x_hat = relu(z@Wd1+bd1)@Wd2+bd2, hdec kept in LDS ----------
// 32-row strip per block, 256 threads, 4 waves (wave-tile 32x64 over columns).
__global__ __launch_bounds__(256) void fused_decoder(
    const unsigned short* __restrict__ Z,    // [N][128] bf16
    const unsigned short* __restrict__ Wt1,  // [512][128] bf16
    const float* __restrict__ b1v,           // [512]
    const unsigned short* __restrict__ Wt2,  // [256][512] bf16
    const float* __restrict__ b2v,           // [256]
    float* __restrict__ Xh, int M)           // [N][256] f32
{
    __shared__ unsigned short z_s[4096];     // [32 rows][16 slots of 8], slot = kc ^ (r&15)
    __shared__ unsigned short hd_s[16384];   // [32 rows][64 chunks of 8], slot = kc ^ (r&7)
    __shared__ unsigned short b_s[16384];    // [256 rows][8 slots of 8]; reused as f32 Cst[32][256]

    const int t = threadIdx.x;
    const int l = t & 63;
    const int w = t >> 6;
    const int bm = blockIdx.x * 32;

    // ---- stage z strip: 8 segs of 1KB (4 rows each); wave w does segs {w, w+4} ----
#pragma unroll
    for (int ii = 0; ii < 2; ++ii) {
        const int seg = w + ii * 4;
        const int r   = seg * 4 + (l >> 4);
        const int sl  = l & 15;
        const int gr  = min(bm + r, M - 1);
        gload16(Z + (size_t)gr * 128 + ((sl ^ (r & 15)) * 8), &z_s[seg * 512]);
    }

    // stage a [256 rows][64 k] weight tile into b_s (32 segs of 8 rows)
    auto stageB = [&](const unsigned short* W, int Krow, int rowbase, int k0) {
#pragma unroll
        for (int ii = 0; ii < 8; ++ii) {
            const int seg = w + ii * 4;
            const int rr  = seg * 8 + (l >> 3);
            const int sl  = l & 7;
            gload16(W + (size_t)(rowbase + rr) * Krow + k0 + ((sl ^ (rr & 7)) * 8),
                    &b_s[seg * 512]);
        }
    };

    f32x4 acc[2][4];

    // ================= phase 1: hd = relu(z @ Wd1^T + bd1), kept in LDS =================
#pragma unroll
    for (int p = 0; p < 4; ++p) {
        const int nc = p >> 1, st = p & 1;       // nc: 256-col chunk; st: K half (K=128)
        stageB(Wt1, 128, nc * 256, st * 64);
        __syncthreads();                          // z (p=0) + B tile ready
        if (st == 0) {
#pragma unroll
            for (int mf = 0; mf < 2; ++mf)
#pragma unroll
                for (int nf = 0; nf < 4; ++nf) acc[mf][nf] = (f32x4)(0.f);
        }
#pragma unroll
        for (int kk = 0; kk < 2; ++kk) {
            const int kc  = st * 8 + kk * 4 + (l >> 4);   // z chunk 0..15
            const int kc2 = kk * 4 + (l >> 4);            // staged-B chunk 0..7
            short8 af[2], bf[4];
#pragma unroll
            for (int mf = 0; mf < 2; ++mf) {
                const int r = mf * 16 + (l & 15);
                af[mf] = *reinterpret_cast<const short8*>(&z_s[r * 128 + ((kc ^ (r & 15)) * 8)]);
            }
#pragma unroll
            for (int nf = 0; nf < 4; ++nf) {
                const int r = w * 64 + nf * 16 + (l & 15);
                bf[nf] = *reinterpret_cast<const short8*>(&b_s[r * 64 + ((kc2 ^ (r & 7)) * 8)]);
            }
#pragma unroll
            for (int mf = 0; mf < 2; ++mf)
#pragma unroll
                for (int nf = 0; nf < 4; ++nf)
                    acc[mf][nf] = __builtin_amdgcn_mfma_f32_16x16x32_bf16(
                        af[mf], bf[nf], acc[mf][nf], 0, 0, 0);
        }
        if (st == 1) {
            // bias + relu + bf16 -> hd (swizzled for phase-2 reads)
#pragma unroll
            for (int mf = 0; mf < 2; ++mf)
#pragma unroll
                for (int nf = 0; nf < 4; ++nf) {
                    const int c  = nc * 256 + w * 64 + nf * 16 + (l & 15);
                    const float bv = b1v[c];
#pragma unroll
                    for (int rr = 0; rr < 4; ++rr) {
                        const int r = mf * 16 + (l >> 4) * 4 + rr;
                        const float v = fmaxf(acc[mf][nf][rr] + bv, 0.f);
                        hd_s[r * 512 + (((c >> 3) ^ (r & 7)) * 8) + (c & 7)] = f2bf(v);
                    }
                }
        }
        __syncthreads();                          // b_s reads done before next stage
    }

    // ================= phase 2: x_hat = hd @ Wd2^T + bd2 (A from LDS) =================
#pragma unroll
    for (int mf = 0; mf < 2; ++mf)
#pragma unroll
        for (int nf = 0; nf < 4; ++nf) acc[mf][nf] = (f32x4)(0.f);

    for (int step = 0; step < 8; ++step) {        // K=512
        stageB(Wt2, 512, 0, step * 64);
        __syncthreads();
#pragma unroll
        for (int kk = 0; kk < 2; ++kk) {
            const int kc  = step * 8 + kk * 4 + (l >> 4); // hd chunk 0..63
            const int kc2 = kk * 4 + (l >> 4);
            short8 af[2], bf[4];
#pragma unroll
            for (int mf = 0; mf < 2; ++mf) {
                const int r = mf * 16 + (l & 15);
                af[mf] = *reinterpret_cast<const short8*>(&hd_s[r * 512 + ((kc ^ (r & 7)) * 8)]);
            }
#pragma unroll
            for (int nf = 0; nf < 4; ++nf) {
                const int r = w * 64 + nf * 16 + (l & 15);
                bf[nf] = *reinterpret_cast<const short8*>(&b_s[r * 64 + ((kc2 ^ (r & 7)) * 8)]);
            }
#pragma unroll
            for (int mf = 0; mf < 2; ++mf)
#pragma unroll
                for (int nf = 0; nf < 4; ++nf)
                    acc[mf][nf] = __builtin_amdgcn_mfma_f32_16x16x32_bf16(
                        af[mf], bf[nf], acc[mf][nf], 0, 0, 0);
        }
        __syncthreads();                          // b_s reads done before next stage
    }

    // ---- epilogue: acc -> f32 Cst (reuses b_s), coalesced bias+store ----
    float* Cst = reinterpret_cast<float*>(b_s);   // [32][256]
#pragma unroll
    for (int mf = 0; mf < 2; ++mf)
#pragma unroll
        for (int nf = 0; nf < 4; ++nf)
#pragma unroll
            for (int rr = 0; rr < 4; ++rr) {
                const int r = mf * 16 + (l >> 4) * 4 + rr;
                const int c = w * 64 + nf * 16 + (l & 15);
                Cst[r * 256 + c] = acc[mf][nf][rr];
            }
    __syncthreads();
#pragma unroll
    for (int it = 0; it < 8; ++it) {
        const int idx = it * 1024 + t * 4;
        const int r = idx >> 8, c = idx & 255;
        if (bm + r < M) {
            float4 v = *reinterpret_cast<const float4*>(&Cst[idx]);
            float4 b = *reinterpret_cast<const float4*>(&b2v[c]);
            v.x += b.x; v.y += b.y; v.z += b.z; v.w += b.w;
            *reinterpret_cast<float4*>(&Xh[(size_t)(bm + r) * 256 + c]) = v;
        }
    }
}

// ---------------- CSR build (XCD-chunked) ----------------
__global__ void hist_kernel(const int* __restrict__ dst, int* __restrict__ counts,
                            int E, int csz)
{
    const int chunk = blockIdx.x & 7;
    const int blk   = blockIdx.x >> 3;
    const int lo = chunk * csz, hi = lo + csz;
    const int base = (blk * TPB + threadIdx.x) * 4;
    if (base + 3 < E) {
        int4 d4 = *reinterpret_cast<const int4*>(dst + base);
        if (d4.x >= lo && d4.x < hi) atomicAdd(&counts[d4.x], 1);
        if (d4.y >= lo && d4.y < hi) atomicAdd(&counts[d4.y], 1);
        if (d4.z >= lo && d4.z < hi) atomicAdd(&counts[d4.z], 1);
        if (d4.w >= lo && d4.w < hi) atomicAdd(&counts[d4.w], 1);
    } else {
        for (int e = base; e < E; ++e) {
            const int d = dst[e];
            if (d >= lo && d < hi) atomicAdd(&counts[d], 1);
        }
    }
}

__global__ void scan1_kernel(const int* __restrict__ counts,
                             int* __restrict__ local, int* __restrict__ bsum, int N)
{
    __shared__ int sh[TPB];
    const int t = threadIdx.x;
    const int base = blockIdx.x * 1024 + t * 4;
    int v[4];
#pragma unroll
    for (int i = 0; i < 4; ++i) v[i] = (base + i < N) ? counts[base + i] : 0;
    const int s = v[0] + v[1] + v[2] + v[3];
    sh[t] = s;
    __syncthreads();
    for (int d = 1; d < TPB; d <<= 1) {
        int x = (t >= d) ? sh[t - d] : 0;
        __syncthreads();
        sh[t] += x;
        __syncthreads();
    }
    int run = sh[t] - s;
#pragma unroll
    for (int i = 0; i < 4; ++i) {
        if (base + i < N) local[base + i] = run;
        run += v[i];
    }
    if (t == TPB - 1) bsum[blockIdx.x] = sh[TPB - 1];
}

__global__ void scan2_kernel(int* __restrict__ bsum, int nb)
{
    __shared__ int sh[TPB];
    const int t = threadIdx.x;
    const int v = (t < nb) ? bsum[t] : 0;
    sh[t] = v;
    __syncthreads();
    for (int d = 1; d < TPB; d <<= 1) {
        int x = (t >= d) ? sh[t - d] : 0;
        __syncthreads();
        sh[t] += x;
        __syncthreads();
    }
    if (t < nb) bsum[t] = sh[t] - v;
}

__global__ void scan3_kernel(int* __restrict__ offsets, int* __restrict__ cursor,
                             const int* __restrict__ bsum, int N)
{
    const int i = blockIdx.x * TPB + threadIdx.x;
    if (i < N) {
        const int o = offsets[i] + bsum[i >> 10];
        offsets[i] = o;
        cursor[i]  = o;
    }
}

__global__ void build_perm_kernel(const int* __restrict__ src, const int* __restrict__ dst,
                                  int* __restrict__ cursor, int* __restrict__ perm,
                                  int E, int csz)
{
    const int chunk = blockIdx.x & 7;
    const int blk   = blockIdx.x >> 3;
    const int lo = chunk * csz, hi = lo + csz;
    const int base = (blk * TPB + threadIdx.x) * 4;
    if (base + 3 < E) {
        int4 d4 = *reinterpret_cast<const int4*>(dst + base);
        if (d4.x >= lo && d4.x < hi) { int p = atomicAdd(&cursor[d4.x], 1); perm[p] = src[base + 0]; }
        if (d4.y >= lo && d4.y < hi) { int p = atomicAdd(&cursor[d4.y], 1); perm[p] = src[base + 1]; }
        if (d4.z >= lo && d4.z < hi) { int p = atomicAdd(&cursor[d4.z], 1); perm[p] = src[base + 2]; }
        if (d4.w >= lo && d4.w < hi) { int p = atomicAdd(&cursor[d4.w], 1); perm[p] = src[base + 3]; }
    } else {
        for (int e = base; e < E; ++e) {
            const int d = dst[e];
            if (d >= lo && d < hi) { int p = atomicAdd(&cursor[d], 1); perm[p] = src[e]; }
        }
    }
}

// ---------------- CSR gather aggregation (bf16, chunked, shfl-broadcast) ----------------
template <int F, int CH, bool WRITE_ZF32>
__global__ __launch_bounds__(256) void agg_kernel(
    const uint2* __restrict__ xt,
    const int* __restrict__ offsets, const int* __restrict__ counts,
    const int* __restrict__ perm,
    uint2* __restrict__ out, float* __restrict__ zf32, int N)
{
    constexpr int RU  = F / 4;
    constexpr int L   = RU / CH;
    constexpr int NPB = TPB / L;

    const int chunk = blockIdx.x % CH;
    const int node  = (blockIdx.x / CH) * NPB + threadIdx.x / L;
    const int g     = threadIdx.x % L;
    if (node >= N) return;
    const int col = chunk * L + g;

    const int start = offsets[node];
    const int deg   = counts[node];

    float a0 = 0.f, a1 = 0.f, a2 = 0.f, a3 = 0.f;

    for (int base = 0; base < deg; base += L) {
        const int m = min(L, deg - base);
        const int pidx = perm[start + base + ((g < m) ? g : (m - 1))];
        int j = 0;
        for (; j + 4 <= m; j += 4) {
            const int s0 = __shfl(pidx, j + 0, L);
            const int s1 = __shfl(pidx, j + 1, L);
            const int s2 = __shfl(pidx, j + 2, L);
            const int s3 = __shfl(pidx, j + 3, L);
            const uint2 v0 = xt[(size_t)s0 * RU + col];
            const uint2 v1 = xt[(size_t)s1 * RU + col];
            const uint2 v2 = xt[(size_t)s2 * RU + col];
            const uint2 v3 = xt[(size_t)s3 * RU + col];
            a0 += bflo(v0.x) + bflo(v1.x) + bflo(v2.x) + bflo(v3.x);
            a1 += bfhi(v0.x) + bfhi(v1.x) + bfhi(v2.x) + bfhi(v3.x);
            a2 += bflo(v0.y) + bflo(v1.y) + bflo(v2.y) + bflo(v3.y);
            a3 += bfhi(v0.y) + bfhi(v1.y) + bfhi(v2.y) + bfhi(v3.y);
        }
        for (; j < m; ++j) {
            const int s = __shfl(pidx, j, L);
            const uint2 v = xt[(size_t)s * RU + col];
            a0 += bflo(v.x); a1 += bfhi(v.x);
            a2 += bflo(v.y); a3 += bfhi(v.y);
        }
    }

    const float c = (float)max(deg, 1);
    const uint2 xv = xt[(size_t)node * RU + col];
    const float r0 = fmaxf(a0 / c, 0.f) + bflo(xv.x);
    const float r1 = fmaxf(a1 / c, 0.f) + bfhi(xv.x);
    const float r2 = fmaxf(a2 / c, 0.f) + bflo(xv.y);
    const float r3 = fmaxf(a3 / c, 0.f) + bfhi(xv.y);

    uint2 o;
    o.x = (unsigned int)f2bf(r0) | ((unsigned int)f2bf(r1) << 16);
    o.y = (unsigned int)f2bf(r2) | ((unsigned int)f2bf(r3) << 16);
    out[(size_t)node * RU + col] = o;
    if (WRITE_ZF32) {
        float4 z4 = make_float4(r0, r1, r2, r3);
        *reinterpret_cast<float4*>(&zf32[(size_t)node * F + 4 * col]) = z4;
    }
}

extern "C" void kernel_launch(void* const* d_in, const int* in_sizes, int n_in,
                              void* d_out, int out_size, void* d_ws, size_t ws_size,
                              hipStream_t stream)
{
    const int IN_DIM = 256, HID = 256, LAT = 128, DEC_HID = 512;
    const int N = in_sizes[0] / IN_DIM;     // 50000
    const int E = in_sizes[1] / 2;          // 800000

    const float* x   = (const float*)d_in[0];
    const int*   ei  = (const int*)d_in[1];
    const float* W1  = (const float*)d_in[2];
    const float* b1  = (const float*)d_in[3];
    const float* W2  = (const float*)d_in[4];
    const float* b2  = (const float*)d_in[5];
    const float* Wd1 = (const float*)d_in[6];
    const float* bd1 = (const float*)d_in[7];
    const float* Wd2 = (const float*)d_in[8];
    const float* bd2 = (const float*)d_in[9];

    const int* src = ei;
    const int* dst = ei + E;

    unsigned short* xt1  = (unsigned short*)d_ws;             // [N][256]
    unsigned short* h    = xt1  + (size_t)N * 256;            // [N][256]
    unsigned short* xt2  = h    + (size_t)N * 256;            // [N][128]
    unsigned short* zbf  = xt2  + (size_t)N * 128;            // [N][128]
    unsigned short* hdec = zbf  + (size_t)N * 128;            // [N][512] (unused now)
    unsigned short* wt1  = hdec + (size_t)N * 512;            // [256][256]
    unsigned short* wt2  = wt1  + 256 * 256;                  // [128][256]
    unsigned short* wtd1 = wt2  + 128 * 256;                  // [512][128]
    unsigned short* wtd2 = wtd1 + 512 * 128;                  // [256][512]
    int* counts  = (int*)(wtd2 + 256 * 512);
    int* offsets = counts + N;
    int* cursor  = offsets + N;
    int* bsum    = cursor + N;
    int* perm    = bsum + 256;

    float* out_xhat = (float*)d_out;
    float* out_z    = out_xhat + (size_t)N * IN_DIM;

    dim3 blk(TPB);
    const int mb64 = (N + 63) / 64;
    const int nscan = (N + 1023) / 1024;
    const int csz = (N + 7) / 8;
    const int egrid8 = ((E + TPB * 4 - 1) / (TPB * 4)) * 8;

    // ---- fused weight transpose/convert ----
    {
        const int tiles = (HID/32)*(IN_DIM/32) + (LAT/32)*(HID/32)
                        + (DEC_HID/32)*(LAT/32) + (IN_DIM/32)*(DEC_HID/32);
        transpose_convert_all<<<tiles, dim3(32, 8), 0, stream>>>(
            W1, wt1, IN_DIM, HID,  W2, wt2, HID, LAT,
            Wd1, wtd1, LAT, DEC_HID,  Wd2, wtd2, DEC_HID, IN_DIM);
    }

    // ---- CSR build (XCD-chunked hist + perm) ----
    hipMemsetAsync(counts, 0, (size_t)N * 4, stream);
    hist_kernel<<<egrid8, blk, 0, stream>>>(dst, counts, E, csz);
    scan1_kernel<<<nscan, blk, 0, stream>>>(counts, offsets, bsum, N);
    scan2_kernel<<<1, blk, 0, stream>>>(bsum, nscan);
    scan3_kernel<<<(N + TPB - 1) / TPB, blk, 0, stream>>>(offsets, cursor, bsum, N);
    build_perm_kernel<<<egrid8, blk, 0, stream>>>(src, dst, cursor, perm, E, csz);

    // ---- GCN layer 1 ----
    mfma_gemm4<float, unsigned short, 256, false><<<dim3(mb64, HID / 128), blk, 0, stream>>>(
        x, wt1, b1, xt1, N, HID);
    {   // F=256, CH=4: 128 B/chunk-row = 1 line
        const int ngroups = (N + 15) / 16;
        agg_kernel<256, 4, false><<<ngroups * 4, blk, 0, stream>>>(
            (const uint2*)xt1, offsets, counts, perm, (uint2*)h, nullptr, N);
    }

    // ---- GCN layer 2 ----
    mfma_gemm4<unsigned short, unsigned short, 256, false><<<dim3(mb64, LAT / 128), blk, 0, stream>>>(
        h, wt2, b2, xt2, N, LAT);
    {   // F=128, CH=2: 128 B/chunk-row = 1 line
        const int ngroups = (N + 15) / 16;
        agg_kernel<128, 2, true><<<ngroups * 2, blk, 0, stream>>>(
            (const uint2*)xt2, offsets, counts, perm, (uint2*)zbf, out_z, N);
    }

    // ---- fused decoder: x_hat = relu(z@Wd1+bd1)@Wd2+bd2 ----
    fused_decoder<<<(N + 31) / 32, blk, 0, stream>>>(
        zbf, wtd1, bd1, wtd2, bd2, out_xhat, N);
}